// Round 11
// baseline (103.633 us; speedup 1.0000x reference)
//
#include <hip/hip_runtime.h>

#define NPART 4096
#define NBATCH 2
#define MAXC 128

// ---------------------------------------------------------------------------
// L1: fused bounds + cell ids + FINAL stable rank + full scatter.
// Grid: NBATCH*256 = 512 blocks; block (b, g) owns particles i = g*16..g*16+15.
//  - redundant batch min/max + verified f32 bounds math (bit-exact, R6/R7)
//  - all 4096 cell ids of the batch into LDS (verified schedule, R7)
//  - rank_i = #{j : c_j < c_i or (c_j==c_i and j<i)}: 16 threads per i scan
//    256 j's each (rotated start -> conflict-free banks), shfl_down reduce
//    (verified, R7)
//  - scatter (no cross-block dep): q==0 writes idxs/locs_s/slocs at r;
//    all 16 threads write data_s[dst*16+q] (coalesced 64B reads/segment
//    writes). sq = (x*x + y*y) + z*z rn mul/add (no fma; verified).
// ---------------------------------------------------------------------------
__global__ __launch_bounds__(256) void rank_scat_kernel(
    const float* __restrict__ locs, const float* __restrict__ data,
    float* __restrict__ out_idxs, float* __restrict__ out_locs,
    float* __restrict__ out_data, float4* __restrict__ slocs) {
  const int bx = blockIdx.x;
  const int tid = threadIdx.x;
  const int b = bx >> 8;
  const int g = bx & 255;

  __shared__ float smn[3][256];
  __shared__ float smx[3][256];
  __shared__ int scj[NPART];  // 16 KB
  __shared__ float sb_lower[3];
  __shared__ int sb_gdi[3];

  const float* base = locs + (size_t)b * NPART * 3;

  // --- batch min/max reduce (proven bit-exact pattern) ---
  float mn0 = 1e30f, mn1 = 1e30f, mn2 = 1e30f;
  float mx0 = -1e30f, mx1 = -1e30f, mx2 = -1e30f;
  for (int n = tid; n < NPART; n += 256) {
    float x = base[n * 3 + 0];
    float y = base[n * 3 + 1];
    float z = base[n * 3 + 2];
    mn0 = fminf(mn0, x); mx0 = fmaxf(mx0, x);
    mn1 = fminf(mn1, y); mx1 = fmaxf(mx1, y);
    mn2 = fminf(mn2, z); mx2 = fmaxf(mx2, z);
  }
  smn[0][tid] = mn0; smn[1][tid] = mn1; smn[2][tid] = mn2;
  smx[0][tid] = mx0; smx[1][tid] = mx1; smx[2][tid] = mx2;
  __syncthreads();
  for (int s = 128; s > 0; s >>= 1) {
    if (tid < s) {
      for (int d = 0; d < 3; d++) {
        smn[d][tid] = fminf(smn[d][tid], smn[d][tid + s]);
        smx[d][tid] = fmaxf(smx[d][tid], smx[d][tid + s]);
      }
    }
    __syncthreads();
  }
  if (tid == 0) {
    for (int d = 0; d < 3; d++) {
      float lo = smn[d][0];
      float up = smx[d][0];
      float t = (up - lo) / 0.1f;               // fp32 IEEE div
      t = fminf(fmaxf(t, 0.0f), 96.0f);         // clip to [0, MAX_GRID_DIM]
      float gdim = ceilf(t);
      float ctr = (lo + up) * 0.5f;
      float l2 = ctr - ((gdim * 0.1f) * 0.5f);  // center - grid_dims*R*0.5
      float g2 = fmaxf(gdim, 1.0f);
      sb_lower[d] = l2;
      sb_gdi[d] = (int)g2;
    }
  }
  __syncthreads();

  // --- cell ids for all 4096 particles (verified f32 schedule) ---
  for (int k = 0; k < 16; k++) {
    int n = tid + k * 256;
    int c[3];
    for (int d = 0; d < 3; d++) {
      float v = base[n * 3 + d];
      float cf = floorf((v - sb_lower[d]) / 0.1f);
      float gdf = (float)sb_gdi[d];
      cf = fminf(fmaxf(cf, 0.0f), gdf - 1.0f);
      c[d] = (int)cf;
    }
    scj[n] = (c[0] * sb_gdi[1] + c[1]) * sb_gdi[2] + c[2];
  }
  __syncthreads();

  // --- final stable rank: thread (il, q); q scans j in [q*256, q*256+256) ---
  const int lane = tid & 63;
  const int il = tid >> 4;        // 0..15
  const int q = tid & 15;         // 0..15
  const int i = g * 16 + il;      // particle (within batch)
  const int ci = scj[i];
  int cnt = 0;
  const int jb = q * 256;
#pragma unroll 8
  for (int it = 0; it < 256; it++) {
    int j = jb + ((it + q) & 255);  // rotated start -> conflict-free banks
    int cj = scj[j];
    cnt += (cj < ci) || (cj == ci && j < i);
  }
  cnt += __shfl_down(cnt, 8);
  cnt += __shfl_down(cnt, 4);
  cnt += __shfl_down(cnt, 2);
  cnt += __shfl_down(cnt, 1);
  const int r = __shfl(cnt, lane & ~15);  // broadcast group-leader sum

  // --- scatter: everything except neighbors ---
  const size_t dst = (size_t)b * NPART + r;
  if (q == 0) {
    float x = base[i * 3 + 0];
    float y = base[i * 3 + 1];
    float z = base[i * 3 + 2];
    float sq = __fadd_rn(__fadd_rn(__fmul_rn(x, x), __fmul_rn(y, y)),
                         __fmul_rn(z, z));
    out_idxs[dst] = (float)i;
    out_locs[dst * 3 + 0] = x;
    out_locs[dst * 3 + 1] = y;
    out_locs[dst * 3 + 2] = z;
    slocs[dst] = make_float4(x, y, z, sq);
  }
  // data_s: lane-per-element, coalesced reads (addr = base + lane*4B)
  out_data[dst * 16 + q] = data[((size_t)b * NPART + i) * 16 + q];
}

// ---------------------------------------------------------------------------
// L2 (PROVEN R10): neighbor lists. 8 rows/block, 2 rows/wave, 32 KB LDS
// staged in 2 halves via async global_load_lds width=16 (wave-uniform base +
// lane*16, m104-safe). unroll 4 -> multiple outstanding ds_read_b128.
//   dot = fma(z*z', fma(y*y', rn(x*x'))); d2 = rn(sq_n+sq_m) - rn(2*dot);
//   hit = d2 <= 0.01f  (verified bit-exact schedule)
// Ordered append via ballot + prefix popcount; -1 padding to MAXC.
// ---------------------------------------------------------------------------
__global__ __launch_bounds__(256) void nbr_kernel(
    const float4* __restrict__ slocs, float* __restrict__ out_nbr) {
  const int b = blockIdx.y;
  __shared__ float4 sl[2048];  // 32 KB
  const int tid = threadIdx.x;
  const int wave = tid >> 6, lane = tid & 63;
  const int row0 = blockIdx.x * 8 + wave * 2;
  const float4* sb = slocs + (size_t)b * NPART;
  const float4 me0 = sb[row0 + 0];
  const float4 me1 = sb[row0 + 1];
  float* r0 = out_nbr + ((size_t)b * NPART + row0) * MAXC;
  float* r1 = r0 + MAXC;
  int c0 = 0, c1 = 0;
  const unsigned long long lmask = (1ull << lane) - 1ull;
  for (int half = 0; half < 2; half++) {
    const int hbase = half * 2048;
    __syncthreads();
    for (int k = 0; k < 8; k++) {
      int j = k * 256 + tid;
      __builtin_amdgcn_global_load_lds(
          (const __attribute__((address_space(1))) unsigned int*)(sb + hbase +
                                                                  j),
          (__attribute__((address_space(3))) unsigned int*)&sl[j], 16, 0, 0);
    }
    __syncthreads();  // compiler emits s_waitcnt vmcnt(0) before barrier
#pragma unroll 4
    for (int base = 0; base < 2048; base += 64) {
      float4 o = sl[base + lane];
      float fm = (float)(hbase + base + lane);
#define DO_ROW(ME, CN, RP)                                                  \
      {                                                                     \
        float dot = __fmaf_rn(ME.z, o.z,                                    \
                     __fmaf_rn(ME.y, o.y, __fmul_rn(ME.x, o.x)));           \
        float d2 = __fsub_rn(__fadd_rn(ME.w, o.w), __fmul_rn(2.0f, dot));   \
        bool hit = d2 <= 0.01f;                                             \
        unsigned long long bal = __ballot(hit);                             \
        int pos = CN + __popcll(bal & lmask);                               \
        if (hit && pos < MAXC) RP[pos] = fm;                                \
        CN += __popcll(bal);                                                \
      }
      DO_ROW(me0, c0, r0)
      DO_ROW(me1, c1, r1)
#undef DO_ROW
    }
  }
  for (int p = min(c0, MAXC) + lane; p < MAXC; p += 64) r0[p] = -1.0f;
  for (int p = min(c1, MAXC) + lane; p < MAXC; p += 64) r1[p] = -1.0f;
}

// ---------------------------------------------------------------------------
extern "C" void kernel_launch(void* const* d_in, const int* in_sizes, int n_in,
                              void* d_out, int out_size, void* d_ws,
                              size_t ws_size, hipStream_t stream) {
  const float* locs = (const float*)d_in[0];  // [2,4096,3]
  const float* data = (const float*)d_in[1];  // [2,4096,16]

  float* out = (float*)d_out;
  float* out_idxs = out;                                      // [2,4096]
  float* out_nbr = out + NBATCH * NPART;                      // [2,4096,128]
  float* out_locs = out_nbr + (size_t)NBATCH * NPART * MAXC;  // [2,4096,3]
  float* out_data = out_locs + (size_t)NBATCH * NPART * 3;    // [2,4096,16]

  // Workspace: slocs float4[8192] @ 0 (128 KB).
  float4* slocs = (float4*)d_ws;

  rank_scat_kernel<<<NBATCH * 256, 256, 0, stream>>>(
      locs, data, out_idxs, out_locs, out_data, slocs);
  nbr_kernel<<<dim3(NPART / 8, NBATCH), 256, 0, stream>>>(slocs, out_nbr);
}

// Round 12
// 89.776 us; speedup vs baseline: 1.1543x; 1.1543x over previous
//
#include <hip/hip_runtime.h>

#define NPART 4096
#define NBATCH 2
#define MAXC 128

// ---------------------------------------------------------------------------
// Kernel 1 (PROVEN R6): fused bounds + cell-id + stable-rank partial counts.
// Block (b, ic, jslice): redundant batch min/max (order-independent ->
// bit-identical), verified f32 bounds math, inline cell ids, non-atomic u16
// partial counts (no zeroing dependency).
// ---------------------------------------------------------------------------
__global__ __launch_bounds__(256) void rank_kernel(
    const float* __restrict__ locs, unsigned short* __restrict__ partial,
    int njlog2, int jspan) {
  const int bx = blockIdx.x;
  const int tid = threadIdx.x;
  const int jslice = bx & ((1 << njlog2) - 1);
  const int ic = (bx >> njlog2) & 15;
  const int b = bx >> (njlog2 + 4);

  __shared__ float smn[3][256];
  __shared__ float smx[3][256];
  __shared__ int scj[256];
  __shared__ float sb_lower[3];
  __shared__ int sb_gdi[3];

  const float* base = locs + (size_t)b * NPART * 3;
  float mn0 = 1e30f, mn1 = 1e30f, mn2 = 1e30f;
  float mx0 = -1e30f, mx1 = -1e30f, mx2 = -1e30f;
  for (int n = tid; n < NPART; n += 256) {
    float x = base[n * 3 + 0];
    float y = base[n * 3 + 1];
    float z = base[n * 3 + 2];
    mn0 = fminf(mn0, x); mx0 = fmaxf(mx0, x);
    mn1 = fminf(mn1, y); mx1 = fmaxf(mx1, y);
    mn2 = fminf(mn2, z); mx2 = fmaxf(mx2, z);
  }
  smn[0][tid] = mn0; smn[1][tid] = mn1; smn[2][tid] = mn2;
  smx[0][tid] = mx0; smx[1][tid] = mx1; smx[2][tid] = mx2;
  __syncthreads();
  for (int s = 128; s > 0; s >>= 1) {
    if (tid < s) {
      for (int d = 0; d < 3; d++) {
        smn[d][tid] = fminf(smn[d][tid], smn[d][tid + s]);
        smx[d][tid] = fmaxf(smx[d][tid], smx[d][tid + s]);
      }
    }
    __syncthreads();
  }
  if (tid == 0) {
    for (int d = 0; d < 3; d++) {
      float lo = smn[d][0];
      float up = smx[d][0];
      float t = (up - lo) / 0.1f;               // fp32 IEEE div
      t = fminf(fmaxf(t, 0.0f), 96.0f);         // clip to [0, MAX_GRID_DIM]
      float gdim = ceilf(t);
      float ctr = (lo + up) * 0.5f;
      float l2 = ctr - ((gdim * 0.1f) * 0.5f);  // center - grid_dims*R*0.5
      float g = fmaxf(gdim, 1.0f);
      sb_lower[d] = l2;
      sb_gdi[d] = (int)g;
    }
  }
  __syncthreads();

  auto cid = [&](int n) {
    int c[3];
    for (int d = 0; d < 3; d++) {
      float v = base[n * 3 + d];
      float cf = floorf((v - sb_lower[d]) / 0.1f);
      float gdf = (float)sb_gdi[d];
      cf = fminf(fmaxf(cf, 0.0f), gdf - 1.0f);
      c[d] = (int)cf;
    }
    return (c[0] * sb_gdi[1] + c[1]) * sb_gdi[2] + c[2];
  };

  const int ci = cid(ic * 256 + tid);
  int cnt = 0;
  for (int jj = 0; jj < jspan; jj++) {
    int jc = jslice * jspan + jj;
    __syncthreads();
    scj[tid] = cid(jc * 256 + tid);
    __syncthreads();
    if (jc < ic) {
#pragma unroll 8
      for (int j = 0; j < 256; j++) cnt += (scj[j] <= ci);
    } else if (jc > ic) {
#pragma unroll 8
      for (int j = 0; j < 256; j++) cnt += (scj[j] < ci);
    } else {
#pragma unroll 8
      for (int j = 0; j < 256; j++) {
        int cj = scj[j];
        cnt += (cj < ci) || (cj == ci && j < tid);
      }
    }
  }
  partial[(size_t)jslice * (NBATCH * NPART) + b * NPART + ic * 256 + tid] =
      (unsigned short)cnt;
}

// ---------------------------------------------------------------------------
// Kernel 2 (PROVEN R6): sum rank partials -> r; scatter idxs/locs_s/data_s/
// slocs at r. sq = (x*x + y*y) + z*z rn mul/add (no fma).
// ---------------------------------------------------------------------------
__global__ __launch_bounds__(256) void scatgather_kernel(
    const float* __restrict__ locs, const float* __restrict__ data,
    const unsigned short* __restrict__ partial, int nj,
    float* __restrict__ out_idxs, float* __restrict__ out_locs,
    float* __restrict__ out_data, float4* __restrict__ slocs) {
  int p = blockIdx.x * 256 + threadIdx.x;  // [0, NBATCH*NPART)
  int pb = p >> 12;
  int i = p & (NPART - 1);
  int r = 0;
  for (int s = 0; s < nj; s++)
    r += (int)partial[(size_t)s * (NBATCH * NPART) + p];
  const float* src = locs + (size_t)p * 3;
  float x = src[0], y = src[1], z = src[2];
  float sq = __fadd_rn(__fadd_rn(__fmul_rn(x, x), __fmul_rn(y, y)),
                       __fmul_rn(z, z));
  size_t dst = (size_t)pb * NPART + r;
  out_idxs[dst] = (float)i;
  out_locs[dst * 3 + 0] = x;
  out_locs[dst * 3 + 1] = y;
  out_locs[dst * 3 + 2] = z;
  slocs[dst] = make_float4(x, y, z, sq);
  const float4* dsrc = (const float4*)(data + (size_t)p * 16);
  float4* ddst = (float4*)(out_data + dst * 16);
  for (int k = 0; k < 4; k++) ddst[k] = dsrc[k];
}

// ---------------------------------------------------------------------------
// Kernel 3 (PROVEN R10): neighbor lists. 8 rows/block, 2 rows/wave, 32 KB
// LDS staged in 2 halves via async global_load_lds width=16 (wave-uniform
// base + lane*16, m104-safe). unroll 4 -> multiple outstanding ds_read_b128.
//   dot = fma(z*z', fma(y*y', rn(x*x'))); d2 = rn(sq_n+sq_m) - rn(2*dot);
//   hit = d2 <= 0.01f  (verified bit-exact schedule)
// Ordered append via ballot + prefix popcount; -1 padding to MAXC.
// ---------------------------------------------------------------------------
__global__ __launch_bounds__(256) void nbr_kernel(
    const float4* __restrict__ slocs, float* __restrict__ out_nbr) {
  const int b = blockIdx.y;
  __shared__ float4 sl[2048];  // 32 KB
  const int tid = threadIdx.x;
  const int wave = tid >> 6, lane = tid & 63;
  const int row0 = blockIdx.x * 8 + wave * 2;
  const float4* sb = slocs + (size_t)b * NPART;
  const float4 me0 = sb[row0 + 0];
  const float4 me1 = sb[row0 + 1];
  float* r0 = out_nbr + ((size_t)b * NPART + row0) * MAXC;
  float* r1 = r0 + MAXC;
  int c0 = 0, c1 = 0;
  const unsigned long long lmask = (1ull << lane) - 1ull;
  for (int half = 0; half < 2; half++) {
    const int hbase = half * 2048;
    __syncthreads();
    for (int k = 0; k < 8; k++) {
      int j = k * 256 + tid;
      __builtin_amdgcn_global_load_lds(
          (const __attribute__((address_space(1))) unsigned int*)(sb + hbase +
                                                                  j),
          (__attribute__((address_space(3))) unsigned int*)&sl[j], 16, 0, 0);
    }
    __syncthreads();  // compiler emits s_waitcnt vmcnt(0) before barrier
#pragma unroll 4
    for (int base = 0; base < 2048; base += 64) {
      float4 o = sl[base + lane];
      float fm = (float)(hbase + base + lane);
#define DO_ROW(ME, CN, RP)                                                  \
      {                                                                     \
        float dot = __fmaf_rn(ME.z, o.z,                                    \
                     __fmaf_rn(ME.y, o.y, __fmul_rn(ME.x, o.x)));           \
        float d2 = __fsub_rn(__fadd_rn(ME.w, o.w), __fmul_rn(2.0f, dot));   \
        bool hit = d2 <= 0.01f;                                             \
        unsigned long long bal = __ballot(hit);                             \
        int pos = CN + __popcll(bal & lmask);                               \
        if (hit && pos < MAXC) RP[pos] = fm;                                \
        CN += __popcll(bal);                                                \
      }
      DO_ROW(me0, c0, r0)
      DO_ROW(me1, c1, r1)
#undef DO_ROW
    }
  }
  for (int q = min(c0, MAXC) + lane; q < MAXC; q += 64) r0[q] = -1.0f;
  for (int q = min(c1, MAXC) + lane; q < MAXC; q += 64) r1[q] = -1.0f;
}

// ---------------------------------------------------------------------------
extern "C" void kernel_launch(void* const* d_in, const int* in_sizes, int n_in,
                              void* d_out, int out_size, void* d_ws,
                              size_t ws_size, hipStream_t stream) {
  const float* locs = (const float*)d_in[0];  // [2,4096,3]
  const float* data = (const float*)d_in[1];  // [2,4096,16]

  float* out = (float*)d_out;
  float* out_idxs = out;                                      // [2,4096]
  float* out_nbr = out + NBATCH * NPART;                      // [2,4096,128]
  float* out_locs = out_nbr + (size_t)NBATCH * NPART * MAXC;  // [2,4096,3]
  float* out_data = out_locs + (size_t)NBATCH * NPART * 3;    // [2,4096,16]

  // Workspace: slocs float4[8192] @ 0 (128 KB), partial u16[NJ*8192] after.
  float4* slocs = (float4*)d_ws;
  unsigned short* partial =
      (unsigned short*)((char*)d_ws + (size_t)NBATCH * NPART * 16);

  size_t base_bytes = (size_t)NBATCH * NPART * 16;
  int nj, njlog2;
  if (ws_size >= base_bytes + 16ull * NBATCH * NPART * 2) {
    nj = 16; njlog2 = 4;
  } else {
    nj = 4; njlog2 = 2;
  }
  int jspan = 16 / nj;

  rank_kernel<<<NBATCH * 16 * nj, 256, 0, stream>>>(locs, partial, njlog2,
                                                    jspan);
  scatgather_kernel<<<NBATCH * NPART / 256, 256, 0, stream>>>(
      locs, data, partial, nj, out_idxs, out_locs, out_data, slocs);
  nbr_kernel<<<dim3(NPART / 8, NBATCH), 256, 0, stream>>>(slocs, out_nbr);
}